// Round 1
// 616.453 us; speedup vs baseline: 1.1607x; 1.1607x over previous
//
#include <hip/hip_runtime.h>
#include <hip/hip_bf16.h>
#include <math.h>

#define B_   4
#define T_   2048
#define C_   1024
#define H_   8
#define DH   128
#define DFF  4096
#define M_   (B_*T_)   // 8192 rows

typedef __attribute__((ext_vector_type(8))) short bf16x8;
typedef __attribute__((ext_vector_type(4))) float f32x4;
typedef __attribute__((ext_vector_type(2))) unsigned int u32x2;

// sqrt(128) * log2(e): scores computed directly in exp2 domain
#define SC2 16.32223094f

__device__ __forceinline__ unsigned short f2bf(float x) {
  union { float f; unsigned u; } v; v.f = x;
  return (unsigned short)((v.u + 0x7fffu + ((v.u >> 16) & 1u)) >> 16);
}
__device__ __forceinline__ float bf2f(unsigned short h) {
  union { unsigned u; float f; } v; v.u = ((unsigned)h) << 16; return v.f;
}

__device__ __forceinline__ f32x4 mfma_bf16(bf16x8 a, bf16x8 b, f32x4 c) {
  return __builtin_amdgcn_mfma_f32_16x16x32_bf16(a, b, c, 0, 0, 0);
}

// async global->LDS, 16B per lane; HW places lane i at wave-base + i*16
__device__ __forceinline__ void gll16(const void* g, void* l) {
  __builtin_amdgcn_global_load_lds((const __attribute__((address_space(1))) void*)g,
                                   (__attribute__((address_space(3))) void*)l,
                                   16, 0, 0);
}

// ---------------------------------------------------------------------------
// LayerNorm: one block per row, 256 threads; emits hi/lo split bf16.
// ---------------------------------------------------------------------------
__global__ __launch_bounds__(256) void ln_kernel(const float* __restrict__ in,
                                                 const float* __restrict__ g,
                                                 const float* __restrict__ bb,
                                                 unsigned short* __restrict__ h_hi,
                                                 unsigned short* __restrict__ h_lo) {
  __shared__ float red[8];
  const int row = blockIdx.x;
  const int tid = threadIdx.x;
  const float* p = in + (size_t)row * C_;
  const float4 xv = *(const float4*)(p + (tid << 2));
  float s  = xv.x + xv.y + xv.z + xv.w;
  float sq = xv.x*xv.x + xv.y*xv.y + xv.z*xv.z + xv.w*xv.w;
  #pragma unroll
  for (int off = 32; off > 0; off >>= 1) {
    s  += __shfl_xor(s, off);
    sq += __shfl_xor(sq, off);
  }
  if ((tid & 63) == 0) { red[(tid >> 6) * 2] = s; red[(tid >> 6) * 2 + 1] = sq; }
  __syncthreads();
  s  = red[0] + red[2] + red[4] + red[6];
  sq = red[1] + red[3] + red[5] + red[7];
  const float mu  = s * (1.0f / C_);
  const float var = sq * (1.0f / C_) - mu * mu;
  const float rs  = rsqrtf(var + 1e-5f);
  const float4 gv = *(const float4*)(g  + (tid << 2));
  const float4 bv = *(const float4*)(bb + (tid << 2));
  float ov[4];
  ov[0] = (xv.x - mu) * rs * gv.x + bv.x;
  ov[1] = (xv.y - mu) * rs * gv.y + bv.y;
  ov[2] = (xv.z - mu) * rs * gv.z + bv.z;
  ov[3] = (xv.w - mu) * rs * gv.w + bv.w;
  ushort4 hv, lv;
  unsigned short* hp = (unsigned short*)&hv;
  unsigned short* lp = (unsigned short*)&lv;
  #pragma unroll
  for (int j = 0; j < 4; ++j) {
    hp[j] = f2bf(ov[j]);
    lp[j] = f2bf(ov[j] - bf2f(hp[j]));
  }
  *(ushort4*)(h_hi + (size_t)row * C_ + (tid << 2)) = hv;
  *(ushort4*)(h_lo + (size_t)row * C_ + (tid << 2)) = lv;
}

// ---------------------------------------------------------------------------
// Weight converters (transpose to n-major k-contiguous bf16).
// ---------------------------------------------------------------------------
__global__ __launch_bounds__(256) void cvt_t_kernel(const float* __restrict__ in,
                                                    unsigned short* __restrict__ out,
                                                    int R, int CC) {
  __shared__ float tile[32][33];
  const int r0 = blockIdx.y << 5, c0 = blockIdx.x << 5;
  const int tr = threadIdx.x >> 3, tc4 = (threadIdx.x & 7) << 2;
  const float4 vv = *(const float4*)(in + (size_t)(r0 + tr) * CC + c0 + tc4);
  tile[tr][tc4+0] = vv.x; tile[tr][tc4+1] = vv.y;
  tile[tr][tc4+2] = vv.z; tile[tr][tc4+3] = vv.w;
  __syncthreads();
  ushort4 o;
  o.x = f2bf(tile[tc4+0][tr]); o.y = f2bf(tile[tc4+1][tr]);
  o.z = f2bf(tile[tc4+2][tr]); o.w = f2bf(tile[tc4+3][tr]);
  *(ushort4*)(out + (size_t)(c0 + tr) * R + r0 + tc4) = o;
}

// split hi/lo transpose for wq/wk/wv: in [H][C][DH] -> out[z][DH][C], z=which*8+h
__global__ __launch_bounds__(256) void cvt_qkv_kernel(const float* __restrict__ wq,
                                                      const float* __restrict__ wk,
                                                      const float* __restrict__ wv,
                                                      unsigned short* __restrict__ wt_hi,
                                                      unsigned short* __restrict__ wt_lo) {
  const int z = blockIdx.z;
  const int which = z >> 3, head = z & 7;
  const float* in = (which == 0 ? wq : (which == 1 ? wk : wv)) + (size_t)head * C_ * DH;
  unsigned short* oh = wt_hi + (size_t)z * DH * C_;
  unsigned short* ol = wt_lo + (size_t)z * DH * C_;
  __shared__ float tile[32][33];
  const int r0 = blockIdx.y << 5, c0 = blockIdx.x << 5;   // r over C, c over DH
  const int tr = threadIdx.x >> 3, tc4 = (threadIdx.x & 7) << 2;
  const float4 vv = *(const float4*)(in + (size_t)(r0 + tr) * DH + c0 + tc4);
  tile[tr][tc4+0] = vv.x; tile[tr][tc4+1] = vv.y;
  tile[tr][tc4+2] = vv.z; tile[tr][tc4+3] = vv.w;
  __syncthreads();
  ushort4 hv, lv;
  unsigned short* hp = (unsigned short*)&hv;
  unsigned short* lp = (unsigned short*)&lv;
  #pragma unroll
  for (int j = 0; j < 4; ++j) {
    const float val = tile[tc4+j][tr];
    hp[j] = f2bf(val);
    lp[j] = f2bf(val - bf2f(hp[j]));
  }
  *(ushort4*)(oh + (size_t)(c0 + tr) * C_ + r0 + tc4) = hv;
  *(ushort4*)(ol + (size_t)(c0 + tr) * C_ + r0 + tc4) = lv;
}

// ---------------------------------------------------------------------------
// MFMA GEMM core: 128x128 tile, BK=32, 256 threads (4 waves, 2x2 wave grid).
// A [M][K] k-contig bf16, B [N][K] k-contig bf16.
// TERMS=3: Ah*Bh + Ah*Bl + Al*Bh split-precision.
// ---------------------------------------------------------------------------
template<int TERMS>
__device__ __forceinline__ void gemm128_mfma(
    const unsigned short* __restrict__ Ah, const unsigned short* __restrict__ Al,
    int lda,
    const unsigned short* __restrict__ Bh, const unsigned short* __restrict__ Bl,
    int ldb, int K, f32x4 (&acc)[4][4],
    unsigned short* AhS, unsigned short* AlS,
    unsigned short* BhS, unsigned short* BlS) {
  const int tid  = threadIdx.x;
  const int w    = tid >> 6;
  const int lane = tid & 63;
  const int l15  = lane & 15, quad = lane >> 4;
  const int srow = lane >> 2, skc = (lane & 3) << 3;
  const int wm = w & 1, wn = w >> 1;

  for (int k0 = 0; k0 < K; k0 += 32) {
    __syncthreads();
    #pragma unroll
    for (int i = 0; i < 2; ++i) {
      const int seg  = w * 2 + i;
      const int r    = seg * 16 + srow;
      const int lofs = seg * 512 + lane * 8;
      gll16(Ah + (size_t)r * lda + k0 + skc, AhS + lofs);
      gll16(Bh + (size_t)r * ldb + k0 + skc, BhS + lofs);
      if (TERMS == 3) {
        gll16(Al + (size_t)r * lda + k0 + skc, AlS + lofs);
        gll16(Bl + (size_t)r * ldb + k0 + skc, BlS + lofs);
      }
    }
    __syncthreads();
    bf16x8 aH[4], bH[4], aL[4], bL[4];
    #pragma unroll
    for (int t = 0; t < 4; ++t) {
      aH[t] = *(const bf16x8*)&AhS[(wm * 64 + t * 16 + l15) * 32 + quad * 8];
      bH[t] = *(const bf16x8*)&BhS[(wn * 64 + t * 16 + l15) * 32 + quad * 8];
      if (TERMS == 3) {
        aL[t] = *(const bf16x8*)&AlS[(wm * 64 + t * 16 + l15) * 32 + quad * 8];
        bL[t] = *(const bf16x8*)&BlS[(wn * 64 + t * 16 + l15) * 32 + quad * 8];
      }
    }
    #pragma unroll
    for (int rt = 0; rt < 4; ++rt)
      #pragma unroll
      for (int ct = 0; ct < 4; ++ct) {
        if (TERMS == 3) {
          acc[rt][ct] = mfma_bf16(aL[rt], bH[ct], acc[rt][ct]);
          acc[rt][ct] = mfma_bf16(aH[rt], bL[ct], acc[rt][ct]);
        }
        acc[rt][ct] = mfma_bf16(aH[rt], bH[ct], acc[rt][ct]);
      }
  }
}

// ---------------------------------------------------------------------------
// QK projection (split precision). grid = (M/128=64, 2*H=16).
// which==0: q out [bh][t][d] bf16 hi/lo, PRE-SCALED by SC2 (exp2-domain).
// which==1: k out tile-image [bh][64 kt][4 kc][32 key][32 d] bf16 hi/lo.
// ---------------------------------------------------------------------------
__global__ __launch_bounds__(256) void qkm_kernel(const unsigned short* __restrict__ h_hi,
                                                  const unsigned short* __restrict__ h_lo,
                                                  const unsigned short* __restrict__ wt_hi,
                                                  const unsigned short* __restrict__ wt_lo,
                                                  unsigned short* __restrict__ q_hi,
                                                  unsigned short* __restrict__ q_lo,
                                                  unsigned short* __restrict__ k_hi,
                                                  unsigned short* __restrict__ k_lo) {
  __shared__ __align__(16) unsigned short AhS[4096], AlS[4096];
  __shared__ __align__(16) unsigned short BhS[4096], BlS[4096];
  const int m0 = blockIdx.x << 7;
  const int z  = blockIdx.y;
  const int which = z >> 3, head = z & 7;
  f32x4 acc[4][4];
  #pragma unroll
  for (int i = 0; i < 4; ++i)
    #pragma unroll
    for (int j = 0; j < 4; ++j)
      #pragma unroll
      for (int r = 0; r < 4; ++r) acc[i][j][r] = 0.f;
  gemm128_mfma<3>(h_hi + (size_t)m0 * C_, h_lo + (size_t)m0 * C_, C_,
                  wt_hi + (size_t)z * DH * C_, wt_lo + (size_t)z * DH * C_, C_,
                  C_, acc, AhS, AlS, BhS, BlS);
  const int lane = threadIdx.x & 63, w = threadIdx.x >> 6;
  const int l15 = lane & 15, quad = lane >> 4;
  const int wm = w & 1, wn = w >> 1;
  const int bh = (m0 >> 11) * H_ + head;
  const int tbase = (m0 & (T_ - 1)) + wm * 64 + quad * 4;
  if (which == 0) {
    #pragma unroll
    for (int rt = 0; rt < 4; ++rt)
      #pragma unroll
      for (int ct = 0; ct < 4; ++ct) {
        const int d = wn * 64 + ct * 16 + l15;
        #pragma unroll
        for (int r = 0; r < 4; ++r) {
          const int t = tbase + rt * 16 + r;
          const float val = acc[rt][ct][r] * SC2;
          const unsigned short hb = f2bf(val);
          const size_t idx = ((size_t)bh * T_ + t) * DH + d;
          q_hi[idx] = hb;
          q_lo[idx] = f2bf(val - bf2f(hb));
        }
      }
  } else {
    #pragma unroll
    for (int rt = 0; rt < 4; ++rt)
      #pragma unroll
      for (int ct = 0; ct < 4; ++ct) {
        const int d = wn * 64 + ct * 16 + l15;
        #pragma unroll
        for (int r = 0; r < 4; ++r) {
          const int t = tbase + rt * 16 + r;
          const float val = acc[rt][ct][r];
          const unsigned short hb = f2bf(val);
          const size_t idx = (((size_t)bh * 64 + (t >> 5)) * 4 + (d >> 5)) * 1024
                           + (size_t)(t & 31) * 32 + (d & 31);
          k_hi[idx] = hb;
          k_lo[idx] = f2bf(val - bf2f(hb));
        }
      }
  }
}

// ---------------------------------------------------------------------------
// V projection (plain bf16). grid = (M/128=64, H=8).
// v out tile-image [bh][64 kt][128 d][32 key] bf16.
// ---------------------------------------------------------------------------
__global__ __launch_bounds__(256) void vm_kernel(const unsigned short* __restrict__ h_hi,
                                                 const unsigned short* __restrict__ wv_hi,
                                                 unsigned short* __restrict__ vimg) {
  __shared__ __align__(16) unsigned short AhS[4096], BhS[4096];
  const int m0 = blockIdx.x << 7;
  const int head = blockIdx.y;
  f32x4 acc[4][4];
  #pragma unroll
  for (int i = 0; i < 4; ++i)
    #pragma unroll
    for (int j = 0; j < 4; ++j)
      #pragma unroll
      for (int r = 0; r < 4; ++r) acc[i][j][r] = 0.f;
  gemm128_mfma<1>(h_hi + (size_t)m0 * C_, nullptr, C_,
                  wv_hi + (size_t)(16 + head) * DH * C_, nullptr, C_,
                  C_, acc, AhS, nullptr, BhS, nullptr);
  const int lane = threadIdx.x & 63, w = threadIdx.x >> 6;
  const int l15 = lane & 15, quad = lane >> 4;
  const int wm = w & 1, wn = w >> 1;
  const int bh = (m0 >> 11) * H_ + head;
  #pragma unroll
  for (int rt = 0; rt < 4; ++rt)
    #pragma unroll
    for (int ct = 0; ct < 4; ++ct) {
      const int d  = wn * 64 + ct * 16 + l15;
      const int t0 = (m0 & (T_ - 1)) + wm * 64 + rt * 16 + quad * 4;
      ushort4 pk;
      pk.x = f2bf(acc[rt][ct][0]); pk.y = f2bf(acc[rt][ct][1]);
      pk.z = f2bf(acc[rt][ct][2]); pk.w = f2bf(acc[rt][ct][3]);
      *(ushort4*)&vimg[(((size_t)bh * 64 + (t0 >> 5)) * 128 + d) * 32 + (t0 & 31)] = pk;
    }
}

// ---------------------------------------------------------------------------
// FF1: ff1 = bf16(relu(h2 @ w1 + b1)).  grid = (DFF/128=32, M/128=64)
// ---------------------------------------------------------------------------
__global__ __launch_bounds__(256) void ff1_kernel(const unsigned short* __restrict__ h2,
                                                  const unsigned short* __restrict__ w1t,
                                                  const float* __restrict__ b1,
                                                  unsigned short* __restrict__ ff1) {
  __shared__ __align__(16) unsigned short AhS[4096], BhS[4096];
  const int n0 = blockIdx.x << 7;
  const int m0 = blockIdx.y << 7;
  f32x4 acc[4][4];
  #pragma unroll
  for (int i = 0; i < 4; ++i)
    #pragma unroll
    for (int j = 0; j < 4; ++j)
      #pragma unroll
      for (int r = 0; r < 4; ++r) acc[i][j][r] = 0.f;
  gemm128_mfma<1>(h2 + (size_t)m0 * C_, nullptr, C_,
                  w1t + (size_t)n0 * C_, nullptr, C_,
                  C_, acc, AhS, nullptr, BhS, nullptr);
  const int lane = threadIdx.x & 63, w = threadIdx.x >> 6;
  const int l15 = lane & 15, quad = lane >> 4;
  const int wm = w & 1, wn = w >> 1;
  #pragma unroll
  for (int rt = 0; rt < 4; ++rt)
    #pragma unroll
    for (int ct = 0; ct < 4; ++ct) {
      const int n = n0 + wn * 64 + ct * 16 + l15;
      const float bias = b1[n];
      #pragma unroll
      for (int r = 0; r < 4; ++r) {
        const int m = m0 + wm * 64 + rt * 16 + quad * 4 + r;
        ff1[(size_t)m * DFF + n] = f2bf(fmaxf(acc[rt][ct][r] + bias, 0.f));
      }
    }
}

// ---------------------------------------------------------------------------
// FF2: out = ff1 @ w2 + b2 + xo.  grid = (C/128=8, M/128=64)
// ---------------------------------------------------------------------------
__global__ __launch_bounds__(256) void ff2_kernel(const unsigned short* __restrict__ ff1,
                                                  const unsigned short* __restrict__ w2t,
                                                  const float* __restrict__ b2,
                                                  const float* __restrict__ xo,
                                                  float* __restrict__ out) {
  __shared__ __align__(16) unsigned short AhS[4096], BhS[4096];
  const int n0 = blockIdx.x << 7;
  const int m0 = blockIdx.y << 7;
  f32x4 acc[4][4];
  #pragma unroll
  for (int i = 0; i < 4; ++i)
    #pragma unroll
    for (int j = 0; j < 4; ++j)
      #pragma unroll
      for (int r = 0; r < 4; ++r) acc[i][j][r] = 0.f;
  gemm128_mfma<1>(ff1 + (size_t)m0 * DFF, nullptr, DFF,
                  w2t + (size_t)n0 * DFF, nullptr, DFF,
                  DFF, acc, AhS, nullptr, BhS, nullptr);
  const int lane = threadIdx.x & 63, w = threadIdx.x >> 6;
  const int l15 = lane & 15, quad = lane >> 4;
  const int wm = w & 1, wn = w >> 1;
  #pragma unroll
  for (int rt = 0; rt < 4; ++rt)
    #pragma unroll
    for (int ct = 0; ct < 4; ++ct) {
      const int n = n0 + wn * 64 + ct * 16 + l15;
      const float bias = b2[n];
      #pragma unroll
      for (int r = 0; r < 4; ++r) {
        const int m = m0 + wm * 64 + rt * 16 + quad * 4 + r;
        out[(size_t)m * C_ + n] = acc[rt][ct][r] + bias + xo[(size_t)m * C_ + n];
      }
    }
}

// ---------------------------------------------------------------------------
// MFMA flash attention, swapped-operand QK^T (S^T = K Q^T so softmax rows are
// lane-local), BK=64 key tiles, defer-max rescale (THR=8 in log2 domain),
// XOR-swizzled P staging (8B writes, conflict-free-ish).
// BQ=128 (4 waves x 32 q-rows). grid = (T/128=16, B*H=32), 256 threads.
// LDS: Kh/Kl/Vt/P = 4 x 16KB = 64KB -> 2 blocks/CU.
// ---------------------------------------------------------------------------
#define BQ 128

__global__ __launch_bounds__(256, 2) void attn_kernel(
    const unsigned short* __restrict__ q_hi, const unsigned short* __restrict__ q_lo,
    const unsigned short* __restrict__ k_hi, const unsigned short* __restrict__ k_lo,
    const unsigned short* __restrict__ vimg,
    const float* __restrict__ x, float* __restrict__ xo) {
  __shared__ __align__(16) unsigned short KhS[8192];   // 2 key-tiles [2][4 kc][32 key][32 d]
  __shared__ __align__(16) unsigned short KlS[8192];
  __shared__ __align__(16) unsigned short VtS[8192];   // 2 key-tiles [2][128 d][32 key]
  __shared__ __align__(16) unsigned short PS [8192];   // [128 q][64 key], 16B-slot XOR swizzle

  const int bh  = blockIdx.y;
  const int qt0 = blockIdx.x * BQ;
  const int tid  = threadIdx.x;
  const int w    = tid >> 6;
  const int lane = tid & 63;
  const int l15  = lane & 15;
  const int quad = lane >> 4;
  // shfl source (+r) to fetch per-q stats (held at lane l15==q) into O-row lanes
  const int srcbase = quad * 20;   // = (quad<<4) + quad*4; + r -> lane with l15 = quad*4+r

  // ---- Q fragments (pre-scaled hi/lo bf16), direct global loads ----
  bf16x8 Qh[2][4], Ql[2][4];
  #pragma unroll
  for (int rt = 0; rt < 2; ++rt) {
    const int row = qt0 + w * 32 + rt * 16 + l15;
    #pragma unroll
    for (int kc = 0; kc < 4; ++kc) {
      const size_t off = ((size_t)bh * T_ + row) * DH + kc * 32 + quad * 8;
      Qh[rt][kc] = *(const bf16x8*)(q_hi + off);
      Ql[rt][kc] = *(const bf16x8*)(q_lo + off);
    }
  }

  f32x4 O[2][8];
  #pragma unroll
  for (int rt = 0; rt < 2; ++rt)
    #pragma unroll
    for (int n = 0; n < 8; ++n)
      #pragma unroll
      for (int r = 0; r < 4; ++r) O[rt][n][r] = 0.f;
  float m_cur[2] = { -1e30f, -1e30f };   // running max for q = rt*16+l15 (log2 units)
  float l_cur[2] = { 0.f, 0.f };

  for (int kt = 0; kt < T_ / 64; ++kt) {
    const size_t tb = ((size_t)bh * 64 + kt * 2) * 4096;
    __syncthreads();   // prior tile's LDS reads complete before overwrite
    #pragma unroll
    for (int i = 0; i < 4; ++i) {
      const int ofs = (w * 4 + i) * 512 + lane * 8;
      gll16(k_hi + tb + ofs, KhS + ofs);
      gll16(k_lo + tb + ofs, KlS + ofs);
      gll16(vimg + tb + ofs, VtS + ofs);
    }
    __syncthreads();

    // ---- S^T = K Q^T (3-term split). C: row=key=ct*16+quad*4+r, col=q=rt*16+l15
    f32x4 S[4][2];
    #pragma unroll
    for (int ct = 0; ct < 4; ++ct)
      #pragma unroll
      for (int rt = 0; rt < 2; ++rt)
        #pragma unroll
        for (int r = 0; r < 4; ++r) S[ct][rt][r] = 0.f;
    __builtin_amdgcn_s_setprio(1);
    #pragma unroll
    for (int kc = 0; kc < 4; ++kc) {
      #pragma unroll
      for (int ct = 0; ct < 4; ++ct) {
        const int o = (ct >> 1) * 4096 + kc * 1024 + (((ct & 1) << 4) + l15) * 32 + quad * 8;
        const bf16x8 kh = *(const bf16x8*)&KhS[o];
        const bf16x8 kl = *(const bf16x8*)&KlS[o];
        #pragma unroll
        for (int rt = 0; rt < 2; ++rt) {
          S[ct][rt] = mfma_bf16(kl, Qh[rt][kc], S[ct][rt]);
          S[ct][rt] = mfma_bf16(kh, Ql[rt][kc], S[ct][rt]);
          S[ct][rt] = mfma_bf16(kh, Qh[rt][kc], S[ct][rt]);
        }
      }
    }
    __builtin_amdgcn_s_setprio(0);

    // ---- per-q tile max: in-lane tree over 16 + 2 shfl_xor across quads ----
    float mx[2];
    #pragma unroll
    for (int rt = 0; rt < 2; ++rt) {
      const float c0 = fmaxf(fmaxf(S[0][rt][0], S[0][rt][1]), fmaxf(S[0][rt][2], S[0][rt][3]));
      const float c1 = fmaxf(fmaxf(S[1][rt][0], S[1][rt][1]), fmaxf(S[1][rt][2], S[1][rt][3]));
      const float c2 = fmaxf(fmaxf(S[2][rt][0], S[2][rt][1]), fmaxf(S[2][rt][2], S[2][rt][3]));
      const float c3 = fmaxf(fmaxf(S[3][rt][0], S[3][rt][1]), fmaxf(S[3][rt][2], S[3][rt][3]));
      float m0 = fmaxf(fmaxf(c0, c1), fmaxf(c2, c3));
      m0 = fmaxf(m0, __shfl_xor(m0, 16));
      m0 = fmaxf(m0, __shfl_xor(m0, 32));
      mx[rt] = m0;
    }

    // ---- defer-max: rescale only when the running max grew by > 8 (log2) ----
    const int need = (mx[0] > m_cur[0] + 8.f) || (mx[1] > m_cur[1] + 8.f);
    if (__any(need)) {
      #pragma unroll
      for (int rt = 0; rt < 2; ++rt) {
        const float mn = fmaxf(m_cur[rt], mx[rt]);
        const float al = exp2f(m_cur[rt] - mn);
        m_cur[rt] = mn;
        l_cur[rt] *= al;
        #pragma unroll
        for (int r = 0; r < 4; ++r) {
          const float ar = __shfl(al, srcbase + r);   // alpha for O-row q=quad*4+r
          #pragma unroll
          for (int n = 0; n < 8; ++n) O[rt][n][r] *= ar;
        }
      }
    }

    // ---- P = exp2(S - m), truncation-pack to bf16, swizzled 8B LDS writes ----
    #pragma unroll
    for (int rt = 0; rt < 2; ++rt) {
      const int rowb = (w * 32 + rt * 16 + l15) * 128;   // PS row byte offset
      float rs = 0.f;
      #pragma unroll
      for (int ct = 0; ct < 4; ++ct) {
        const float p0 = exp2f(S[ct][rt][0] - m_cur[rt]);
        const float p1 = exp2f(S[ct][rt][1] - m_cur[rt]);
        const float p2 = exp2f(S[ct][rt][2] - m_cur[rt]);
        const float p3 = exp2f(S[ct][rt][3] - m_cur[rt]);
        rs += (p0 + p1) + (p2 + p3);
        u32x2 uu;
        uu.x = (__float_as_uint(p1) & 0xffff0000u) | (__float_as_uint(p0) >> 16);
        uu.y = (__float_as_uint(p3) & 0xffff0000u) | (__float_as_uint(p2) >> 16);
        const int slot = (ct * 2 + (quad >> 1)) ^ (l15 & 7);   // 16B-slot XOR swizzle
        *(u32x2*)((char*)PS + rowb + (slot << 4) + ((quad & 1) << 3)) = uu;
      }
      rs += __shfl_xor(rs, 16);
      rs += __shfl_xor(rs, 32);
      l_cur[rt] += rs;
    }
    // PS is wave-private (rows w*32..w*32+31): no barrier needed; compiler
    // inserts the lgkmcnt wait for the aliasing ds_read below.

    // ---- O += P V ----
    __builtin_amdgcn_s_setprio(1);
    #pragma unroll
    for (int kc = 0; kc < 2; ++kc) {
      bf16x8 aP[2];
      #pragma unroll
      for (int rt = 0; rt < 2; ++rt) {
        const int rowb = (w * 32 + rt * 16 + l15) * 128;
        const int slot = (kc * 4 + quad) ^ (l15 & 7);
        aP[rt] = *(const bf16x8*)((const char*)PS + rowb + (slot << 4));
      }
      #pragma unroll
      for (int n = 0; n < 8; ++n) {
        const bf16x8 bv = *(const bf16x8*)&VtS[kc * 4096 + (n * 16 + l15) * 32 + quad * 8];
        O[0][n] = mfma_bf16(aP[0], bv, O[0][n]);
        O[1][n] = mfma_bf16(aP[1], bv, O[1][n]);
      }
    }
    __builtin_amdgcn_s_setprio(0);
  }

  // ---- epilogue: xo = x + O / l  (l held at lane l15==q -> shfl to O rows) ----
  const int b = bh >> 3, hh = bh & 7;
  #pragma unroll
  for (int rt = 0; rt < 2; ++rt) {
    #pragma unroll
    for (int r = 0; r < 4; ++r) {
      const float lr = __shfl(l_cur[rt], srcbase + r);
      const float inv_l = 1.0f / lr;
      const int t = qt0 + w * 32 + rt * 16 + quad * 4 + r;
      const size_t xrow = ((size_t)(b * T_ + t)) * C_ + (size_t)hh * DH;
      #pragma unroll
      for (int n = 0; n < 8; ++n) {
        const int d = n * 16 + l15;
        xo[xrow + d] = x[xrow + d] + O[rt][n][r] * inv_l;
      }
    }
  }
}

// ---------------------------------------------------------------------------
// Workspace layout (MB offsets):
//   0-32    xo    f32 [M][C]
//   32-48   q_hi  bf16 [bh][t][d] (pre-scaled)   \
//   48-64   q_lo  bf16 [bh][t][d]                 \
//   64-80   k_hi  bf16 image [bh][64][4][32][32]   } ff1 aliases 32-96 after attn
//   80-96   k_lo  bf16 image                      /
//   96-112  vimg  bf16 image [bh][64][128][32]
//   112-128 h_hi  bf16 [M][C]
//   128-144 h_lo  bf16 [M][C]
//   144-152 w1t   bf16 [DFF][C]
//   152-160 w2t   bf16 [C][DFF]
//   160-166 wt_hi bf16 [3H][DH][C]
//   166-172 wt_lo bf16 [3H][DH][C]
// ---------------------------------------------------------------------------
extern "C" void kernel_launch(void* const* d_in, const int* in_sizes, int n_in,
                              void* d_out, int out_size, void* d_ws, size_t ws_size,
                              hipStream_t stream) {
  (void)in_sizes; (void)n_in; (void)out_size; (void)ws_size;
  const float* x     = (const float*)d_in[0];
  const float* wq    = (const float*)d_in[1];
  const float* wk    = (const float*)d_in[2];
  const float* wv    = (const float*)d_in[3];
  const float* w1    = (const float*)d_in[4];
  const float* b1    = (const float*)d_in[5];
  const float* w2    = (const float*)d_in[6];
  const float* b2    = (const float*)d_in[7];
  const float* ln1_g = (const float*)d_in[8];
  const float* ln1_b = (const float*)d_in[9];
  const float* ln2_g = (const float*)d_in[10];
  const float* ln2_b = (const float*)d_in[11];
  float* out = (float*)d_out;

  char* W = (char*)d_ws;
  float* xo = (float*)(W);
  unsigned short* q_hi  = (unsigned short*)(W + (32u  << 20));
  unsigned short* q_lo  = (unsigned short*)(W + (48u  << 20));
  unsigned short* k_hi  = (unsigned short*)(W + (64u  << 20));
  unsigned short* k_lo  = (unsigned short*)(W + (80u  << 20));
  unsigned short* vimg  = (unsigned short*)(W + (96u  << 20));
  unsigned short* ff1   = (unsigned short*)(W + (32u  << 20));   // aliases q/k
  unsigned short* h_hi  = (unsigned short*)(W + (112u << 20));
  unsigned short* h_lo  = (unsigned short*)(W + (128u << 20));
  unsigned short* w1t   = (unsigned short*)(W + (144u << 20));
  unsigned short* w2t   = (unsigned short*)(W + (152u << 20));
  unsigned short* wt_hi = (unsigned short*)(W + (160u << 20));
  unsigned short* wt_lo = (unsigned short*)(W + (166u << 20));

  cvt_t_kernel<<<dim3(DFF / 32, C_ / 32), 256, 0, stream>>>(w1, w1t, C_, DFF);
  cvt_t_kernel<<<dim3(C_ / 32, DFF / 32), 256, 0, stream>>>(w2, w2t, DFF, C_);
  cvt_qkv_kernel<<<dim3(DH / 32, C_ / 32, 24), 256, 0, stream>>>(wq, wk, wv, wt_hi, wt_lo);
  ln_kernel<<<M_, 256, 0, stream>>>(x, ln1_g, ln1_b, h_hi, h_lo);
  qkm_kernel<<<dim3(M_ / 128, 16), 256, 0, stream>>>(h_hi, h_lo, wt_hi, wt_lo,
                                                     q_hi, q_lo, k_hi, k_lo);
  vm_kernel<<<dim3(M_ / 128, H_), 256, 0, stream>>>(h_hi, wt_hi, vimg);
  attn_kernel<<<dim3(T_ / BQ, B_ * H_), 256, 0, stream>>>(q_hi, q_lo, k_hi, k_lo,
                                                          vimg, x, xo);
  ln_kernel<<<M_, 256, 0, stream>>>(xo, ln2_g, ln2_b, h_hi, h_lo);
  ff1_kernel<<<dim3(DFF / 128, M_ / 128), 256, 0, stream>>>(h_hi, w1t, b1, ff1);
  ff2_kernel<<<dim3(C_ / 128, M_ / 128), 256, 0, stream>>>(ff1, w2t, b2, xo, out);
}